// Round 15
// baseline (2968.765 us; speedup 1.0000x reference)
//
#include <hip/hip_runtime.h>
#include <math.h>

// SingleGAP: per-point tiny MLPs + GLOBAL softmax over N (axis 0, faithful bug),
// then attention-weighted sum. out0 = [N][16] x_attn, out1 = [N][160] h2 (flat,
// [F][K] order per point == x2v raw reshape).
//
// K1 (R15): 16 lanes/point, ONE f per lane. R14's failure was AMDGPU
//     promote-alloca moving own[3] into LDS (LDS_Block_Size 12800, 2e8 bank
//     conflicts). Fix: NAMED own0/own1/own2 + three explicit unrolled J-loops
//     (no array => no promotion), unconditional f&7 third load (L1 dedup),
//     32-bit offsets, branchless comb. Live set ~50 regs =>
//     __launch_bounds__(256,8) caps at 64 VGPR = 8 waves/SIMD bucket.
//     Loads 16B sector-major (R11-proven clean); h2 stores [10f,10f+10)
//     float2s (R2-proven clean); swz16 broadcast + sum16 DPP (R13-verified).
// K2: reduce per-block (m,s) -> global (m,s) per k-slot.
// K3: quad-per-point weighted sum: out0 = softmax(logits) @ x2v.

__device__ __forceinline__ void comb(float& m, float& s, float om, float os) {
  float M = fmaxf(m, om);
  if (M == -INFINITY) return;  // both empty
  s = s * __expf(m - M) + os * __expf(om - M);
  m = M;
}

// Broadcast lane (16group_base + B) to all 16 lanes of its group.
// ds_swizzle BitMode: src = (lane & 0x10) | B  (per 32-lane half).
template <int B>
__device__ __forceinline__ float swz16(float v) {
  return __int_as_float(
      __builtin_amdgcn_ds_swizzle(__float_as_int(v), (B << 5) | 0x10));
}

// DPP move (VALU): result[lane] = v[ctrl-mapped lane].
template <int CTRL>
__device__ __forceinline__ float dppmov(float v) {
  return __int_as_float(__builtin_amdgcn_update_dpp(
      0, __float_as_int(v), CTRL, 0xf, 0xf, true));
}

// 16-lane butterfly sum, all-DPP (verified R13): quad xor1 (0xB1), quad xor2
// (0x4E), half-row mirror (0x141), row mirror (0x140).
__device__ __forceinline__ float sum16(float v) {
  v += dppmov<0xB1>(v);
  v += dppmov<0x4E>(v);
  v += dppmov<0x141>(v);
  v += dppmov<0x140>(v);
  return v;
}

__device__ __forceinline__ float f4e(const float4& v, int e) {
  return (e == 0) ? v.x : (e == 1) ? v.y : (e == 2) ? v.z : v.w;
}

// swz16 with switch-resolved constant (src is compile-time under full unroll).
__device__ __forceinline__ float swz16sw(float v, int src) {
  switch (src) {
    case 0:  return swz16<0>(v);
    case 1:  return swz16<1>(v);
    case 2:  return swz16<2>(v);
    case 3:  return swz16<3>(v);
    case 4:  return swz16<4>(v);
    case 5:  return swz16<5>(v);
    case 6:  return swz16<6>(v);
    case 7:  return swz16<7>(v);
    case 8:  return swz16<8>(v);
    case 9:  return swz16<9>(v);
    case 10: return swz16<10>(v);
    case 11: return swz16<11>(v);
    case 12: return swz16<12>(v);
    case 13: return swz16<13>(v);
    case 14: return swz16<14>(v);
    default: return swz16<15>(v);
  }
}

__global__ __launch_bounds__(256, 8) void gap_k1(
    const float* __restrict__ xknn, const float* __restrict__ x,
    const float* __restrict__ Wf, const float* __restrict__ bf,
    const float* __restrict__ W1, const float* __restrict__ b1p,
    float* __restrict__ out, float* __restrict__ partials, int n) {
  __shared__ float s_red[4][10][2];

  const int tid = threadIdx.x;
  const int lane = tid & 63;
  const int wave = tid >> 6;
  const int f = lane & 15;      // owned feature; also load-slot id
  const int g = tid >> 4;       // point-group 0..15 in block

  // own Wf row f (16 VGPR), W1[f], bf[f]
  float wfo[16];
#pragma unroll
  for (int dq = 0; dq < 4; ++dq) {
    float4 v = *(const float4*)(Wf + f * 16 + 4 * dq);
    wfo[4 * dq + 0] = v.x;
    wfo[4 * dq + 1] = v.y;
    wfo[4 * dq + 2] = v.z;
    wfo[4 * dq + 3] = v.w;
  }
  const float w1o = W1[f];
  const float bfo = bf[f];
  // u_own = u[f] = sum_j W1[j] * Wf[j][f]  (column read, prologue-only)
  float u_own = 0.f;
#pragma unroll
  for (int j = 0; j < 16; ++j) u_own = fmaf(W1[j], Wf[j * 16 + f], u_own);
  const float addA = 2.0f * b1p[0];  // global +sb shift is softmax-invariant

  // online softmax state for k == f (valid for f<10)
  float rm = -INFINITY, rs = 0.f;

  float* out0 = out;                       // [n][16]  (logits now, x_attn later)
  float* out1 = out + (size_t)n * 16;      // [n][160] h2 flat ([F][K] per point)

  const unsigned un = (unsigned)n;
  const unsigned pstride = (unsigned)gridDim.x * 16u;

  for (unsigned pt = (unsigned)blockIdx.x * 16u + (unsigned)g; pt < un;
       pt += pstride) {
    const unsigned xb = pt * 160u;
    // 16B sector-major loads (R11-proven clean). NAMED vars: no promote-alloca.
    const float4 own0 = *(const float4*)(xknn + xb + 4 * f);
    const float4 own1 = *(const float4*)(xknn + xb + 64 + 4 * f);
    const float4 own2 = *(const float4*)(xknn + xb + 128 + 4 * (f & 7));
    const float xo = x[pt * 16u + f];

    // acc[k] = bf[f] + sum_d Wf[f][d] * x2[d][k]; element r = 4J+e lives in
    // lane (J mod 16), component e; all indices compile-time (static unroll).
    float acc[10];
#pragma unroll
    for (int k = 0; k < 10; ++k) acc[k] = bfo;
#pragma unroll
    for (int J = 0; J < 16; ++J) {
#pragma unroll
      for (int e = 0; e < 4; ++e) {
        const int r = 4 * J + e, d = r / 10, k = r - d * 10;
        acc[k] = fmaf(wfo[d], swz16sw(f4e(own0, e), J), acc[k]);
      }
    }
#pragma unroll
    for (int J = 16; J < 32; ++J) {
#pragma unroll
      for (int e = 0; e < 4; ++e) {
        const int r = 4 * J + e, d = r / 10, k = r - d * 10;
        acc[k] = fmaf(wfo[d], swz16sw(f4e(own1, e), J - 16), acc[k]);
      }
    }
#pragma unroll
    for (int J = 32; J < 40; ++J) {
#pragma unroll
      for (int e = 0; e < 4; ++e) {
        const int r = 4 * J + e, d = r / 10, k = r - d * 10;
        acc[k] = fmaf(wfo[d], swz16sw(f4e(own2, e), J - 32), acc[k]);
      }
    }

    // h2 -> out1 flat [F][K]: lane's contiguous [10f,10f+10) (R2-proven clean)
    float* o1 = out1 + (xb + 10u * f);
    *(float2*)(o1 + 0) = make_float2(acc[0], acc[1]);
    *(float2*)(o1 + 2) = make_float2(acc[2], acc[3]);
    *(float2*)(o1 + 4) = make_float2(acc[4], acc[5]);
    *(float2*)(o1 + 6) = make_float2(acc[6], acc[7]);
    *(float2*)(o1 + 8) = make_float2(acc[8], acc[9]);

    // fused reduce+select: lane f keeps only tk[f] (no tk[] array)
    float lj = 0.f;
#pragma unroll
    for (int k = 0; k < 10; ++k) {
      const float s = sum16(w1o * acc[k]);   // = sb + a2[k], all lanes
      lj = (k == f) ? s : lj;
    }
    lj += sum16(u_own * xo) + addA;

    if (f < 10) {
      out0[pt * 16u + f] = lj;   // stash logit; K3 overwrites
      // branchless online (m,s): exp(-INF - M) = 0 handles the empty case
      const float M = fmaxf(rm, lj);
      rs = rs * __expf(rm - M) + __expf(lj - M);
      rm = M;
    }
  }

  // (m,s): combine the 4 point-subgroups (lane bits 4,5), then 4 waves
  {
    float om = __shfl_xor(rm, 16), os = __shfl_xor(rs, 16);
    comb(rm, rs, om, os);
    om = __shfl_xor(rm, 32); os = __shfl_xor(rs, 32);
    comb(rm, rs, om, os);
  }
  if (lane < 10) {
    s_red[wave][lane][0] = rm;
    s_red[wave][lane][1] = rs;
  }
  __syncthreads();
  if (tid < 10) {
    float m = s_red[0][tid][0], s = s_red[0][tid][1];
    comb(m, s, s_red[1][tid][0], s_red[1][tid][1]);
    comb(m, s, s_red[2][tid][0], s_red[2][tid][1]);
    comb(m, s, s_red[3][tid][0], s_red[3][tid][1]);
    partials[(size_t)blockIdx.x * 20 + tid * 2 + 0] = m;
    partials[(size_t)blockIdx.x * 20 + tid * 2 + 1] = s;
  }
}

__global__ __launch_bounds__(256) void gap_k2(const float* __restrict__ part,
                                              int nb, float* __restrict__ fin) {
  const int k = blockIdx.x;   // one block per k-slot
  const int tid = threadIdx.x;
  float m = -INFINITY, s = 0.f;
  for (int i = tid; i < nb; i += 256)
    comb(m, s, part[(size_t)i * 20 + k * 2], part[(size_t)i * 20 + k * 2 + 1]);
#pragma unroll
  for (int mask = 1; mask < 64; mask <<= 1) {
    float om = __shfl_xor(m, mask, 64);
    float os = __shfl_xor(s, mask, 64);
    comb(m, s, om, os);
  }
  __shared__ float sm[4][2];
  const int wave = tid >> 6, lane = tid & 63;
  if (lane == 0) { sm[wave][0] = m; sm[wave][1] = s; }
  __syncthreads();
  if (tid == 0) {
    for (int w = 1; w < 4; ++w) comb(m, s, sm[w][0], sm[w][1]);
    fin[k * 2 + 0] = m;
    fin[k * 2 + 1] = s;
  }
}

// K3: 4 lanes per point; lane (p,q) accumulates features f = 4q..4q+3.
// Reads out1 flat at offset k*16+f == x2v[k][f] (raw-reshape identity).
__global__ __launch_bounds__(256) void gap_k3(const float* __restrict__ fin,
                                              float* __restrict__ out, int n) {
  __shared__ float s_fin[20];
  if (threadIdx.x < 20) s_fin[threadIdx.x] = fin[threadIdx.x];
  __syncthreads();
  float mk[10], rsk[10];
#pragma unroll
  for (int k = 0; k < 10; ++k) {
    mk[k] = s_fin[2 * k];
    rsk[k] = 1.0f / s_fin[2 * k + 1];
  }
  float* out0 = out;
  const float* out1 = out + (size_t)n * 16;
  const int q = threadIdx.x & 3;
  const int pl = threadIdx.x >> 2;           // 64 points per block pass
  for (long i = (long)blockIdx.x * 64 + pl; i < n; i += (long)gridDim.x * 64) {
    float* lrow = out0 + i * 16;
    // all 4 lanes of the quad read the same 64B logit line (L1 broadcast)
    float4 la = *(const float4*)(lrow);
    float4 lb = *(const float4*)(lrow + 4);
    float2 lc = *(const float2*)(lrow + 8);
    float l[10] = {la.x, la.y, la.z, la.w, lb.x, lb.y, lb.z, lb.w, lc.x, lc.y};
    float w[10];
#pragma unroll
    for (int k = 0; k < 10; ++k) w[k] = __expf(l[k] - mk[k]) * rsk[k];
    const float* vrow = out1 + i * 160 + q * 4;
    float4 acc = make_float4(0.f, 0.f, 0.f, 0.f);
#pragma unroll
    for (int k = 0; k < 10; ++k) {
      float4 v = *(const float4*)(vrow + k * 16);
      float wk = w[k];
      acc.x = fmaf(wk, v.x, acc.x);
      acc.y = fmaf(wk, v.y, acc.y);
      acc.z = fmaf(wk, v.z, acc.z);
      acc.w = fmaf(wk, v.w, acc.w);
    }
    // store after all reads (wave-lockstep => no RAW hazard on the logit line)
    *(float4*)(lrow + q * 4) = acc;
  }
}

extern "C" void kernel_launch(void* const* d_in, const int* in_sizes, int n_in,
                              void* d_out, int out_size, void* d_ws, size_t ws_size,
                              hipStream_t stream) {
  const float* xknn = (const float*)d_in[0];
  const float* x    = (const float*)d_in[1];
  const float* Wf   = (const float*)d_in[2];
  const float* bf   = (const float*)d_in[3];
  const float* W1   = (const float*)d_in[4];
  const float* b1   = (const float*)d_in[5];
  float* out = (float*)d_out;
  const int n = in_sizes[1] / 16;  // x is [N][16]

  const int G1 = 2048;
  float* partials = (float*)d_ws;                 // [G1][10][2]
  float* finals = partials + (size_t)G1 * 20;     // [10][2]

  gap_k1<<<G1, 256, 0, stream>>>(xknn, x, Wf, bf, W1, b1, out, partials, n);
  gap_k2<<<10, 256, 0, stream>>>(partials, G1, finals);
  gap_k3<<<2048, 256, 0, stream>>>(finals, out, n);
}

// Round 16
// 500.530 us; speedup vs baseline: 5.9312x; 5.9312x over previous
//
#include <hip/hip_runtime.h>
#include <math.h>

// SingleGAP: per-point tiny MLPs + GLOBAL softmax over N (axis 0, faithful bug),
// then attention-weighted sum. out0 = [N][16] x_attn, out1 = [N][160] h2 (flat,
// [F][K] order per point == x2v raw reshape).
//
// K1 (R16 = R2 structure modernized): 32-point tile staged to LDS (coalesced
//     float4 loads -> ds_write_b128, PADDED rows of 164 floats: point stride =
//     4 banks -> the wave's 4 points read distinct banks; 16-lane same-address
//     broadcast is free). Compute: 16 lanes/point, ONE f per lane (VGPR ~45
//     natural -- x2 lives in LDS, not registers; R2 proved 56 VGPR for this
//     class). Math identical to R15 (passed): fused sum16 reduce+select logits,
//     u-trick a1, branchless online (m,s). Single buffer + 7 blocks/CU ->
//     inter-block overlap hides the barrier drain (m114).
// K2: reduce per-block (m,s) -> global (m,s) per k-slot.
// K3: quad-per-point weighted sum: out0 = softmax(logits) @ x2v.

#define TPTS 32              // points per tile
#define ROWF 164             // padded floats per point row (40 float4 + 1 pad)

__device__ __forceinline__ void comb(float& m, float& s, float om, float os) {
  float M = fmaxf(m, om);
  if (M == -INFINITY) return;  // both empty
  s = s * __expf(m - M) + os * __expf(om - M);
  m = M;
}

// DPP move (VALU): result[lane] = v[ctrl-mapped lane].
template <int CTRL>
__device__ __forceinline__ float dppmov(float v) {
  return __int_as_float(__builtin_amdgcn_update_dpp(
      0, __float_as_int(v), CTRL, 0xf, 0xf, true));
}

// 16-lane butterfly sum, all-DPP (verified R13/R15): quad xor1 (0xB1), quad
// xor2 (0x4E), half-row mirror (0x141), row mirror (0x140).
__device__ __forceinline__ float sum16(float v) {
  v += dppmov<0xB1>(v);
  v += dppmov<0x4E>(v);
  v += dppmov<0x141>(v);
  v += dppmov<0x140>(v);
  return v;
}

__device__ __forceinline__ float f4e(const float4& v, int e) {
  return (e == 0) ? v.x : (e == 1) ? v.y : (e == 2) ? v.z : v.w;
}

__global__ __launch_bounds__(256) void gap_k1(
    const float* __restrict__ xknn, const float* __restrict__ x,
    const float* __restrict__ Wf, const float* __restrict__ bf,
    const float* __restrict__ W1, const float* __restrict__ b1p,
    float* __restrict__ out, float* __restrict__ partials, int n) {
  __shared__ float sm[TPTS * ROWF];     // 32 x 164 x 4B = 21 KB
  __shared__ float s_red[4][10][2];

  const int tid = threadIdx.x;
  const int lane = tid & 63;
  const int wave = tid >> 6;
  const int f = lane & 15;      // owned feature
  const int g = tid >> 4;       // compute group 0..15 (point pl = g, g+16)

  // own Wf row f (16 VGPR), W1[f], bf[f]
  float wfo[16];
#pragma unroll
  for (int dq = 0; dq < 4; ++dq) {
    float4 v = *(const float4*)(Wf + f * 16 + 4 * dq);
    wfo[4 * dq + 0] = v.x;
    wfo[4 * dq + 1] = v.y;
    wfo[4 * dq + 2] = v.z;
    wfo[4 * dq + 3] = v.w;
  }
  const float w1o = W1[f];
  const float bfo = bf[f];
  // u_own = u[f] = sum_j W1[j] * Wf[j][f]  (column read, prologue-only)
  float u_own = 0.f;
#pragma unroll
  for (int j = 0; j < 16; ++j) u_own = fmaf(W1[j], Wf[j * 16 + f], u_own);
  const float addA = 2.0f * b1p[0];  // global +sb shift is softmax-invariant

  // online softmax state for k == f (valid for f<10)
  float rm = -INFINITY, rs = 0.f;

  float* out0 = out;                       // [n][16]  (logits now, x_attn later)
  float* out1 = out + (size_t)n * 16;      // [n][160] h2 flat ([F][K] per point)

  const long ntiles = (long)n / TPTS;      // N = 1M: exact (32 | n)

  for (long t = (long)blockIdx.x; t < ntiles; t += gridDim.x) {
    const unsigned base = (unsigned)t * TPTS;       // first point of tile
    __syncthreads();   // prior compute readers done before restage

    // ---- stage: 1280 float4, coalesced 4KB/instr; padded LDS rows ----
    {
      const float* src = xknn + (size_t)base * 160;
#pragma unroll
      for (int i = 0; i < 5; ++i) {
        const int F4 = tid + 256 * i;          // float4 index 0..1279
        const float4 v = *(const float4*)(src + 4 * F4);
        const int p = F4 / 40;                 // point in tile
        const int s4 = F4 - p * 40;            // float4 slot in row
        *(float4*)(&sm[p * ROWF + 4 * s4]) = v;
      }
    }
    __syncthreads();

    // ---- compute: 2 points per group (pl = g, g+16) ----
#pragma unroll
    for (int rep = 0; rep < 2; ++rep) {
      const int pl = g + 16 * rep;
      const unsigned pt = base + (unsigned)pl;
      const float* sp = &sm[pl * ROWF];
      const float xo = x[(size_t)pt * 16 + f];

      float acc[10];
#pragma unroll
      for (int k = 0; k < 10; ++k) acc[k] = bfo;
#pragma unroll
      for (int J = 0; J < 40; ++J) {
        const float4 v = *(const float4*)(sp + 4 * J);   // bcast in 16-group
#pragma unroll
        for (int e = 0; e < 4; ++e) {
          const int r = 4 * J + e, d = r / 10, k = r - d * 10;
          acc[k] = fmaf(wfo[d], f4e(v, e), acc[k]);
        }
      }

      // h2 -> out1 flat [F][K]: lane's contiguous [10f,10f+10) (proven clean)
      float* o1 = out1 + ((size_t)pt * 160 + 10 * f);
      *(float2*)(o1 + 0) = make_float2(acc[0], acc[1]);
      *(float2*)(o1 + 2) = make_float2(acc[2], acc[3]);
      *(float2*)(o1 + 4) = make_float2(acc[4], acc[5]);
      *(float2*)(o1 + 6) = make_float2(acc[6], acc[7]);
      *(float2*)(o1 + 8) = make_float2(acc[8], acc[9]);

      // fused reduce+select: lane f keeps only tk[f] (R15-verified math)
      float lj = 0.f;
#pragma unroll
      for (int k = 0; k < 10; ++k) {
        const float s = sum16(w1o * acc[k]);   // = sb + a2[k], all lanes
        lj = (k == f) ? s : lj;
      }
      lj += sum16(u_own * xo) + addA;

      if (f < 10) {
        out0[(size_t)pt * 16 + f] = lj;   // stash logit; K3 overwrites
        const float M = fmaxf(rm, lj);    // branchless online (m,s)
        rs = rs * __expf(rm - M) + __expf(lj - M);
        rm = M;
      }
    }
  }

  // (m,s): combine the 4 point-subgroups (lane bits 4,5), then 4 waves
  {
    float om = __shfl_xor(rm, 16), os = __shfl_xor(rs, 16);
    comb(rm, rs, om, os);
    om = __shfl_xor(rm, 32); os = __shfl_xor(rs, 32);
    comb(rm, rs, om, os);
  }
  if (lane < 10) {
    s_red[wave][lane][0] = rm;
    s_red[wave][lane][1] = rs;
  }
  __syncthreads();
  if (tid < 10) {
    float m = s_red[0][tid][0], s = s_red[0][tid][1];
    comb(m, s, s_red[1][tid][0], s_red[1][tid][1]);
    comb(m, s, s_red[2][tid][0], s_red[2][tid][1]);
    comb(m, s, s_red[3][tid][0], s_red[3][tid][1]);
    partials[(size_t)blockIdx.x * 20 + tid * 2 + 0] = m;
    partials[(size_t)blockIdx.x * 20 + tid * 2 + 1] = s;
  }
}

__global__ __launch_bounds__(256) void gap_k2(const float* __restrict__ part,
                                              int nb, float* __restrict__ fin) {
  const int k = blockIdx.x;   // one block per k-slot
  const int tid = threadIdx.x;
  float m = -INFINITY, s = 0.f;
  for (int i = tid; i < nb; i += 256)
    comb(m, s, part[(size_t)i * 20 + k * 2], part[(size_t)i * 20 + k * 2 + 1]);
#pragma unroll
  for (int mask = 1; mask < 64; mask <<= 1) {
    float om = __shfl_xor(m, mask, 64);
    float os = __shfl_xor(s, mask, 64);
    comb(m, s, om, os);
  }
  __shared__ float sm[4][2];
  const int wave = tid >> 6, lane = tid & 63;
  if (lane == 0) { sm[wave][0] = m; sm[wave][1] = s; }
  __syncthreads();
  if (tid == 0) {
    for (int w = 1; w < 4; ++w) comb(m, s, sm[w][0], sm[w][1]);
    fin[k * 2 + 0] = m;
    fin[k * 2 + 1] = s;
  }
}

// K3: 4 lanes per point; lane (p,q) accumulates features f = 4q..4q+3.
// Reads out1 flat at offset k*16+f == x2v[k][f] (raw-reshape identity).
__global__ __launch_bounds__(256) void gap_k3(const float* __restrict__ fin,
                                              float* __restrict__ out, int n) {
  __shared__ float s_fin[20];
  if (threadIdx.x < 20) s_fin[threadIdx.x] = fin[threadIdx.x];
  __syncthreads();
  float mk[10], rsk[10];
#pragma unroll
  for (int k = 0; k < 10; ++k) {
    mk[k] = s_fin[2 * k];
    rsk[k] = 1.0f / s_fin[2 * k + 1];
  }
  float* out0 = out;
  const float* out1 = out + (size_t)n * 16;
  const int q = threadIdx.x & 3;
  const int pl = threadIdx.x >> 2;           // 64 points per block pass
  for (long i = (long)blockIdx.x * 64 + pl; i < n; i += (long)gridDim.x * 64) {
    float* lrow = out0 + i * 16;
    // all 4 lanes of the quad read the same 64B logit line (L1 broadcast)
    float4 la = *(const float4*)(lrow);
    float4 lb = *(const float4*)(lrow + 4);
    float2 lc = *(const float2*)(lrow + 8);
    float l[10] = {la.x, la.y, la.z, la.w, lb.x, lb.y, lb.z, lb.w, lc.x, lc.y};
    float w[10];
#pragma unroll
    for (int k = 0; k < 10; ++k) w[k] = __expf(l[k] - mk[k]) * rsk[k];
    const float* vrow = out1 + i * 160 + q * 4;
    float4 acc = make_float4(0.f, 0.f, 0.f, 0.f);
#pragma unroll
    for (int k = 0; k < 10; ++k) {
      float4 v = *(const float4*)(vrow + k * 16);
      float wk = w[k];
      acc.x = fmaf(wk, v.x, acc.x);
      acc.y = fmaf(wk, v.y, acc.y);
      acc.z = fmaf(wk, v.z, acc.z);
      acc.w = fmaf(wk, v.w, acc.w);
    }
    // store after all reads (wave-lockstep => no RAW hazard on the logit line)
    *(float4*)(lrow + q * 4) = acc;
  }
}

extern "C" void kernel_launch(void* const* d_in, const int* in_sizes, int n_in,
                              void* d_out, int out_size, void* d_ws, size_t ws_size,
                              hipStream_t stream) {
  const float* xknn = (const float*)d_in[0];
  const float* x    = (const float*)d_in[1];
  const float* Wf   = (const float*)d_in[2];
  const float* bf   = (const float*)d_in[3];
  const float* W1   = (const float*)d_in[4];
  const float* b1   = (const float*)d_in[5];
  float* out = (float*)d_out;
  const int n = in_sizes[1] / 16;  // x is [N][16]

  const int G1 = 1792;   // 7 blocks/CU x 256 CU (LDS-resident set)
  float* partials = (float*)d_ws;                 // [G1][10][2]
  float* finals = partials + (size_t)G1 * 20;     // [10][2]

  gap_k1<<<G1, 256, 0, stream>>>(xknn, x, Wf, bf, W1, b1, out, partials, n);
  gap_k2<<<10, 256, 0, stream>>>(partials, G1, finals);
  gap_k3<<<2048, 256, 0, stream>>>(finals, out, n);
}

// Round 17
// 499.662 us; speedup vs baseline: 5.9415x; 1.0017x over previous
//
#include <hip/hip_runtime.h>
#include <math.h>

// SingleGAP: per-point tiny MLPs + GLOBAL softmax over N (axis 0, faithful bug),
// then attention-weighted sum. out0 = [N][16] x_attn, out1 = [N][160] h2 (flat,
// [F][K] order per point == x2v raw reshape).
//
// K1 (R17 = R16 + double-buffer + write-late staging): 16-point tiles, TWO
//     padded LDS buffers (2 x 16 x 164 floats ~ 21KB -> still 7 blocks/CU).
//     Per iter: barrier -> issue next tile's 3 float4 loads (write-late; they
//     stay in flight under compute) -> compute buf[cur] (16 lanes/point, one f
//     per lane; R16-verified math) -> ds_write staged regs -> buf[cur^1].
//     Staging regs NAMED st0/st1/st2 (R14 lesson: arrays => promote-alloca).
// K2: reduce per-block (m,s) -> global (m,s) per k-slot.
// K3: quad-per-point weighted sum: out0 = softmax(logits) @ x2v.

#define TPTS 16              // points per tile
#define ROWF 164             // padded floats per point row (40 float4 + 1 pad)

__device__ __forceinline__ void comb(float& m, float& s, float om, float os) {
  float M = fmaxf(m, om);
  if (M == -INFINITY) return;  // both empty
  s = s * __expf(m - M) + os * __expf(om - M);
  m = M;
}

// DPP move (VALU): result[lane] = v[ctrl-mapped lane].
template <int CTRL>
__device__ __forceinline__ float dppmov(float v) {
  return __int_as_float(__builtin_amdgcn_update_dpp(
      0, __float_as_int(v), CTRL, 0xf, 0xf, true));
}

// 16-lane butterfly sum, all-DPP (verified R13/R15/R16).
__device__ __forceinline__ float sum16(float v) {
  v += dppmov<0xB1>(v);
  v += dppmov<0x4E>(v);
  v += dppmov<0x141>(v);
  v += dppmov<0x140>(v);
  return v;
}

__device__ __forceinline__ float f4e(const float4& v, int e) {
  return (e == 0) ? v.x : (e == 1) ? v.y : (e == 2) ? v.z : v.w;
}

__global__ __launch_bounds__(256) void gap_k1(
    const float* __restrict__ xknn, const float* __restrict__ x,
    const float* __restrict__ Wf, const float* __restrict__ bf,
    const float* __restrict__ W1, const float* __restrict__ b1p,
    float* __restrict__ out, float* __restrict__ partials, int n) {
  __shared__ float sm[2][TPTS * ROWF];   // 2 x 16 x 164 floats = 21 KB
  __shared__ float s_red[4][10][2];

  const int tid = threadIdx.x;
  const int lane = tid & 63;
  const int wave = tid >> 6;
  const int f = lane & 15;      // owned feature
  const int g = tid >> 4;       // point-in-tile 0..15

  // staging geometry (fixed per thread): F4 indices tid, tid+256, tid+512(<640)
  const int F0 = tid, F1 = tid + 256, F2 = tid + 512;
  const unsigned l0 = (unsigned)((F0 / 40) * ROWF + (F0 % 40) * 4);
  const unsigned l1 = (unsigned)((F1 / 40) * ROWF + (F1 % 40) * 4);
  const unsigned l2 = (unsigned)((F2 / 40) * ROWF + (F2 % 40) * 4);
  const bool has2 = (F2 < TPTS * 40);    // tid < 128

  // own Wf row f (16 VGPR), W1[f], bf[f]
  float wfo[16];
#pragma unroll
  for (int dq = 0; dq < 4; ++dq) {
    float4 v = *(const float4*)(Wf + f * 16 + 4 * dq);
    wfo[4 * dq + 0] = v.x;
    wfo[4 * dq + 1] = v.y;
    wfo[4 * dq + 2] = v.z;
    wfo[4 * dq + 3] = v.w;
  }
  const float w1o = W1[f];
  const float bfo = bf[f];
  float u_own = 0.f;   // u[f] = sum_j W1[j] Wf[j][f]
#pragma unroll
  for (int j = 0; j < 16; ++j) u_own = fmaf(W1[j], Wf[j * 16 + f], u_own);
  const float addA = 2.0f * b1p[0];  // global +sb shift is softmax-invariant

  float rm = -INFINITY, rs = 0.f;    // online (m,s) for k == f (f<10)

  float* out0 = out;                       // [n][16]  (logits now, x_attn later)
  float* out1 = out + (size_t)n * 16;      // [n][160] h2 flat ([F][K] per point)

  const long ntiles = (long)n / TPTS;      // n = 1M: exact
  const long G = gridDim.x;
  long t = (long)blockIdx.x;
  int cur = 0;

  // NAMED staging regs (R14 lesson: arrays trip promote-alloca)
  float4 st0, st1, st2;

  // prologue: stage first tile into buf 0
  {
    const float* src = xknn + (size_t)t * (TPTS * 160);
    st0 = *(const float4*)(src + 4 * F0);
    st1 = *(const float4*)(src + 4 * F1);
    st2 = st0;
    if (has2) st2 = *(const float4*)(src + 4 * F2);
    *(float4*)(&sm[0][l0]) = st0;
    *(float4*)(&sm[0][l1]) = st1;
    if (has2) *(float4*)(&sm[0][l2]) = st2;
  }

  for (; t < ntiles; t += G) {
    __syncthreads();                  // buf[cur] staged & prior readers done

    const long tn = t + G;
    const bool more = (tn < ntiles);
    if (more) {                       // issue-early: in flight under compute
      const float* src = xknn + (size_t)tn * (TPTS * 160);
      st0 = *(const float4*)(src + 4 * F0);
      st1 = *(const float4*)(src + 4 * F1);
      if (has2) st2 = *(const float4*)(src + 4 * F2);
    }

    // ---- compute point pt = t*16 + g from buf[cur] ----
    const unsigned pt = (unsigned)t * TPTS + (unsigned)g;
    const float* sp = &sm[cur][g * ROWF];
    const float xo = x[(size_t)pt * 16 + f];

    float acc[10];
#pragma unroll
    for (int k = 0; k < 10; ++k) acc[k] = bfo;
#pragma unroll
    for (int J = 0; J < 40; ++J) {
      const float4 v = *(const float4*)(sp + 4 * J);   // bcast in 16-group
#pragma unroll
      for (int e = 0; e < 4; ++e) {
        const int r = 4 * J + e, d = r / 10, k = r - d * 10;
        acc[k] = fmaf(wfo[d], f4e(v, e), acc[k]);
      }
    }

    // h2 -> out1 flat [F][K]: lane's contiguous [10f,10f+10) (proven clean)
    float* o1 = out1 + ((size_t)pt * 160 + 10 * f);
    *(float2*)(o1 + 0) = make_float2(acc[0], acc[1]);
    *(float2*)(o1 + 2) = make_float2(acc[2], acc[3]);
    *(float2*)(o1 + 4) = make_float2(acc[4], acc[5]);
    *(float2*)(o1 + 6) = make_float2(acc[6], acc[7]);
    *(float2*)(o1 + 8) = make_float2(acc[8], acc[9]);

    // fused reduce+select logits (R15/R16-verified math)
    float lj = 0.f;
#pragma unroll
    for (int k = 0; k < 10; ++k) {
      const float s = sum16(w1o * acc[k]);   // = sb + a2[k], all lanes
      lj = (k == f) ? s : lj;
    }
    lj += sum16(u_own * xo) + addA;

    if (f < 10) {
      out0[(size_t)pt * 16 + f] = lj;   // stash logit; K3 overwrites
      const float M = fmaxf(rm, lj);    // branchless online (m,s)
      rs = rs * __expf(rm - M) + __expf(lj - M);
      rm = M;
    }

    // ---- write-late: land next tile into the OTHER buffer ----
    if (more) {
      *(float4*)(&sm[cur ^ 1][l0]) = st0;
      *(float4*)(&sm[cur ^ 1][l1]) = st1;
      if (has2) *(float4*)(&sm[cur ^ 1][l2]) = st2;
    }
    cur ^= 1;
  }

  // (m,s): combine the 4 point-subgroups (lane bits 4,5), then 4 waves
  {
    float om = __shfl_xor(rm, 16), os = __shfl_xor(rs, 16);
    comb(rm, rs, om, os);
    om = __shfl_xor(rm, 32); os = __shfl_xor(rs, 32);
    comb(rm, rs, om, os);
  }
  if (lane < 10) {
    s_red[wave][lane][0] = rm;
    s_red[wave][lane][1] = rs;
  }
  __syncthreads();
  if (tid < 10) {
    float m = s_red[0][tid][0], s = s_red[0][tid][1];
    comb(m, s, s_red[1][tid][0], s_red[1][tid][1]);
    comb(m, s, s_red[2][tid][0], s_red[2][tid][1]);
    comb(m, s, s_red[3][tid][0], s_red[3][tid][1]);
    partials[(size_t)blockIdx.x * 20 + tid * 2 + 0] = m;
    partials[(size_t)blockIdx.x * 20 + tid * 2 + 1] = s;
  }
}

__global__ __launch_bounds__(256) void gap_k2(const float* __restrict__ part,
                                              int nb, float* __restrict__ fin) {
  const int k = blockIdx.x;   // one block per k-slot
  const int tid = threadIdx.x;
  float m = -INFINITY, s = 0.f;
  for (int i = tid; i < nb; i += 256)
    comb(m, s, part[(size_t)i * 20 + k * 2], part[(size_t)i * 20 + k * 2 + 1]);
#pragma unroll
  for (int mask = 1; mask < 64; mask <<= 1) {
    float om = __shfl_xor(m, mask, 64);
    float os = __shfl_xor(s, mask, 64);
    comb(m, s, om, os);
  }
  __shared__ float sm[4][2];
  const int wave = tid >> 6, lane = tid & 63;
  if (lane == 0) { sm[wave][0] = m; sm[wave][1] = s; }
  __syncthreads();
  if (tid == 0) {
    for (int w = 1; w < 4; ++w) comb(m, s, sm[w][0], sm[w][1]);
    fin[k * 2 + 0] = m;
    fin[k * 2 + 1] = s;
  }
}

// K3: 4 lanes per point; lane (p,q) accumulates features f = 4q..4q+3.
// Reads out1 flat at offset k*16+f == x2v[k][f] (raw-reshape identity).
__global__ __launch_bounds__(256) void gap_k3(const float* __restrict__ fin,
                                              float* __restrict__ out, int n) {
  __shared__ float s_fin[20];
  if (threadIdx.x < 20) s_fin[threadIdx.x] = fin[threadIdx.x];
  __syncthreads();
  float mk[10], rsk[10];
#pragma unroll
  for (int k = 0; k < 10; ++k) {
    mk[k] = s_fin[2 * k];
    rsk[k] = 1.0f / s_fin[2 * k + 1];
  }
  float* out0 = out;
  const float* out1 = out + (size_t)n * 16;
  const int q = threadIdx.x & 3;
  const int pl = threadIdx.x >> 2;           // 64 points per block pass
  for (long i = (long)blockIdx.x * 64 + pl; i < n; i += (long)gridDim.x * 64) {
    float* lrow = out0 + i * 16;
    // all 4 lanes of the quad read the same 64B logit line (L1 broadcast)
    float4 la = *(const float4*)(lrow);
    float4 lb = *(const float4*)(lrow + 4);
    float2 lc = *(const float2*)(lrow + 8);
    float l[10] = {la.x, la.y, la.z, la.w, lb.x, lb.y, lb.z, lb.w, lc.x, lc.y};
    float w[10];
#pragma unroll
    for (int k = 0; k < 10; ++k) w[k] = __expf(l[k] - mk[k]) * rsk[k];
    const float* vrow = out1 + i * 160 + q * 4;
    float4 acc = make_float4(0.f, 0.f, 0.f, 0.f);
#pragma unroll
    for (int k = 0; k < 10; ++k) {
      float4 v = *(const float4*)(vrow + k * 16);
      float wk = w[k];
      acc.x = fmaf(wk, v.x, acc.x);
      acc.y = fmaf(wk, v.y, acc.y);
      acc.z = fmaf(wk, v.z, acc.z);
      acc.w = fmaf(wk, v.w, acc.w);
    }
    // store after all reads (wave-lockstep => no RAW hazard on the logit line)
    *(float4*)(lrow + q * 4) = acc;
  }
}

extern "C" void kernel_launch(void* const* d_in, const int* in_sizes, int n_in,
                              void* d_out, int out_size, void* d_ws, size_t ws_size,
                              hipStream_t stream) {
  const float* xknn = (const float*)d_in[0];
  const float* x    = (const float*)d_in[1];
  const float* Wf   = (const float*)d_in[2];
  const float* bf   = (const float*)d_in[3];
  const float* W1   = (const float*)d_in[4];
  const float* b1   = (const float*)d_in[5];
  float* out = (float*)d_out;
  const int n = in_sizes[1] / 16;  // x is [N][16]

  const int G1 = 1792;   // 7 blocks/CU x 256 CU
  float* partials = (float*)d_ws;                 // [G1][10][2]
  float* finals = partials + (size_t)G1 * 20;     // [10][2]

  gap_k1<<<G1, 256, 0, stream>>>(xknn, x, Wf, bf, W1, b1, out, partials, n);
  gap_k2<<<10, 256, 0, stream>>>(partials, G1, finals);
  gap_k3<<<2048, 256, 0, stream>>>(finals, out, n);
}